// Round 1
// baseline (730.099 us; speedup 1.0000x reference)
//
#include <hip/hip_runtime.h>
#include <hip/hip_bf16.h>
#include <cstdint>

// MHA fwd: B=4, L=2048, HIDDEN=1024, HEADS=16, HEAD_DIM=64. fp32 in/out,
// bf16 MFMA internally (fp32 accum everywhere).
#define HIDDEN 1024
#define HEADS 16
#define HEAD_DIM 64
#define BATCH 4
#define SEQ 2048
#define TOK (BATCH * SEQ) /* 8192 */

typedef __attribute__((ext_vector_type(8))) short short8; // 8 bf16 (4 VGPRs)
typedef __attribute__((ext_vector_type(4))) float f32x4;

__device__ __forceinline__ void gload_lds16(const void* g, void* s) {
  // global -> LDS direct, 16B/lane; LDS dest = wave-uniform base + lane*16
  __builtin_amdgcn_global_load_lds(
      (const __attribute__((address_space(1))) void*)g,
      (__attribute__((address_space(3))) void*)s, 16, 0, 0);
}

// ---------------------------------------------------------------- conversions
__global__ __launch_bounds__(256) void convert_f32_bf16(
    const float* __restrict__ in, __hip_bfloat16* __restrict__ out, int n4) {
  int idx = blockIdx.x * blockDim.x + threadIdx.x;
  int stride = gridDim.x * blockDim.x;
  for (int i = idx; i < n4; i += stride) {
    float4 v = ((const float4*)in)[i];
    union { ushort4 u; __hip_bfloat16 h[4]; } r;
    r.h[0] = __float2bfloat16(v.x);
    r.h[1] = __float2bfloat16(v.y);
    r.h[2] = __float2bfloat16(v.z);
    r.h[3] = __float2bfloat16(v.w);
    ((ushort4*)out)[i] = r.u;
  }
}

// W [K=1024][N=1024] fp32 -> Wt [N][K] bf16 (64x64 LDS tile transpose)
__global__ __launch_bounds__(256) void transpose_to_bf16(
    const float* __restrict__ in, __hip_bfloat16* __restrict__ out) {
  __shared__ __hip_bfloat16 t[64][65];
  const int tx = threadIdx.x & 63;
  const int ty = threadIdx.x >> 6; // 0..3
  const int k0 = blockIdx.y * 64;
  const int n0 = blockIdx.x * 64;
#pragma unroll
  for (int i = 0; i < 16; ++i) {
    int r = i * 4 + ty;
    t[r][tx] = __float2bfloat16(in[(size_t)(k0 + r) * 1024 + n0 + tx]);
  }
  __syncthreads();
#pragma unroll
  for (int i = 0; i < 16; ++i) {
    int r = i * 4 + ty;
    out[(size_t)(n0 + r) * 1024 + k0 + tx] = t[tx][r];
  }
}

// ---------------------------------------------------------------- GEMM (m97)
// C[M,N] = A[M,K](bf16) @ Bt[N,K](bf16)^T ; 128x128 tile, BK=32, 4 waves.
// EPI==0: C = acc + bias[n] -> fp32 Cout (ld 1024)
// EPI==1: fused QKV epilogue: n in [0,1024)->Q, [1024,2048)->K  ([B,H,L,D] bf16)
//                             [2048,3072)->V transposed ([B,H,D,L] bf16)
template <int EPI, int KDIM>
__global__ __launch_bounds__(256) void gemm128(
    const __hip_bfloat16* __restrict__ A, const __hip_bfloat16* __restrict__ Bt,
    float* __restrict__ Cout, const float* __restrict__ bias,
    const float* __restrict__ bq, const float* __restrict__ bk,
    const float* __restrict__ bv, __hip_bfloat16* __restrict__ Qb,
    __hip_bfloat16* __restrict__ Kb, __hip_bfloat16* __restrict__ VTb) {
  __shared__ __hip_bfloat16 As[128 * 32];
  __shared__ __hip_bfloat16 Bs[128 * 32];
  const int tid = threadIdx.x;
  const int w = tid >> 6, l = tid & 63;
  const int lc = l & 15, lg = l >> 4;
  const int wr = w >> 1, wc = w & 1;
  const int bm0 = blockIdx.x * 128;
  const int bn0 = blockIdx.y * 128;
  const int lrow = l >> 2;      // row within 16-row chunk
  const int lk = (l & 3) * 8;   // k element offset within 32

  f32x4 acc[4][4] = {};

#pragma unroll 1
  for (int kt = 0; kt < KDIM; kt += 32) {
    if (w < 2) { // waves 0,1 stage A (rows 0..127)
#pragma unroll
      for (int i = 0; i < 4; ++i) {
        int rloc = w * 64 + i * 16;
        const __hip_bfloat16* src =
            A + (size_t)(bm0 + rloc + lrow) * KDIM + kt + lk;
        gload_lds16(src, &As[rloc * 32]);
      }
    } else { // waves 2,3 stage B
#pragma unroll
      for (int i = 0; i < 4; ++i) {
        int rloc = (w - 2) * 64 + i * 16;
        const __hip_bfloat16* src =
            Bt + (size_t)(bn0 + rloc + lrow) * KDIM + kt + lk;
        gload_lds16(src, &Bs[rloc * 32]);
      }
    }
    __syncthreads();
    short8 af[4], bf[4];
#pragma unroll
    for (int mt = 0; mt < 4; ++mt)
      af[mt] = *(const short8*)&As[(wr * 64 + mt * 16 + lc) * 32 + 8 * lg];
#pragma unroll
    for (int nt = 0; nt < 4; ++nt)
      bf[nt] = *(const short8*)&Bs[(wc * 64 + nt * 16 + lc) * 32 + 8 * lg];
#pragma unroll
    for (int mt = 0; mt < 4; ++mt)
#pragma unroll
      for (int nt = 0; nt < 4; ++nt)
        acc[mt][nt] = __builtin_amdgcn_mfma_f32_16x16x32_bf16(
            af[mt], bf[nt], acc[mt][nt], 0, 0, 0);
    __syncthreads();
  }

#pragma unroll
  for (int mt = 0; mt < 4; ++mt) {
#pragma unroll
    for (int nt = 0; nt < 4; ++nt) {
#pragma unroll
      for (int r = 0; r < 4; ++r) {
        int m = bm0 + wr * 64 + mt * 16 + 4 * lg + r;
        int n = bn0 + wc * 64 + nt * 16 + lc;
        float v = acc[mt][nt][r];
        if (EPI == 0) {
          Cout[(size_t)m * 1024 + n] = v + bias[n];
        } else {
          int proj = n >> 10, win = n & 1023, h = win >> 6, d = win & 63;
          const float* bp = (proj == 0) ? bq : ((proj == 1) ? bk : bv);
          __hip_bfloat16 hv = __float2bfloat16(v + bp[win]);
          int b = m >> 11, lq = m & 2047;
          if (proj == 0)
            Qb[((size_t)(b * 16 + h) * 2048 + lq) * 64 + d] = hv;
          else if (proj == 1)
            Kb[((size_t)(b * 16 + h) * 2048 + lq) * 64 + d] = hv;
          else
            VTb[((size_t)(b * 16 + h) * 64 + d) * 2048 + lq] = hv;
        }
      }
    }
  }
}

// ---------------------------------------------------------------- attention
// 4 waves/block; wave w owns 16 q-rows; KVBLK=64; flash online softmax (log2
// domain); P -> XOR-swizzled per-wave LDS strip -> MFMA A-operand for PV.
__global__ __launch_bounds__(256) void attn64(
    const __hip_bfloat16* __restrict__ Qb, const __hip_bfloat16* __restrict__ Kb,
    const __hip_bfloat16* __restrict__ VTb, __hip_bfloat16* __restrict__ AO) {
  __shared__ char Plds[4][2048]; // per-wave [16 q][64 kv] bf16, XOR-swizzled
  const int tid = threadIdx.x;
  const int w = tid >> 6, l = tid & 63;
  const int lc = l & 15, lg = l >> 4;
  const int bh = blockIdx.y; // 0..63
  const int qb = blockIdx.x; // 0..31
  const int b = bh >> 4, h = bh & 15;

  const __hip_bfloat16* Qp = Qb + (size_t)bh * SEQ * 64;
  const __hip_bfloat16* Kp = Kb + (size_t)bh * SEQ * 64;
  const __hip_bfloat16* Vp = VTb + (size_t)bh * 64 * SEQ;

  const int q0 = qb * 64 + w * 16;
  short8 qf0 = *(const short8*)(Qp + (q0 + lc) * 64 + 8 * lg);
  short8 qf1 = *(const short8*)(Qp + (q0 + lc) * 64 + 32 + 8 * lg);

  f32x4 o[4] = {};
  float mrun[4], lrun[4];
#pragma unroll
  for (int r = 0; r < 4; ++r) { mrun[r] = -INFINITY; lrun[r] = 0.0f; }
  const float cs = 0.125f * 1.44269504088896f; // scale * log2(e)

#pragma unroll 1
  for (int kv0 = 0; kv0 < SEQ; kv0 += 64) {
    f32x4 s[4] = {};
#pragma unroll
    for (int kvt = 0; kvt < 4; ++kvt) {
      short8 kf0 = *(const short8*)(Kp + (kv0 + kvt * 16 + lc) * 64 + 8 * lg);
      short8 kf1 =
          *(const short8*)(Kp + (kv0 + kvt * 16 + lc) * 64 + 32 + 8 * lg);
      s[kvt] = __builtin_amdgcn_mfma_f32_16x16x32_bf16(qf0, kf0, s[kvt], 0, 0, 0);
      s[kvt] = __builtin_amdgcn_mfma_f32_16x16x32_bf16(qf1, kf1, s[kvt], 0, 0, 0);
    }
    // row max (raw), 16-lane butterfly within kv direction
    float t[4];
#pragma unroll
    for (int r = 0; r < 4; ++r)
      t[r] = fmaxf(fmaxf(s[0][r], s[1][r]), fmaxf(s[2][r], s[3][r]));
#pragma unroll
    for (int off = 1; off <= 8; off <<= 1)
#pragma unroll
      for (int r = 0; r < 4; ++r) t[r] = fmaxf(t[r], __shfl_xor(t[r], off));

    float p[4][4], corr[4], rs[4];
#pragma unroll
    for (int r = 0; r < 4; ++r) {
      float mn = fmaxf(mrun[r], t[r] * cs);
      corr[r] = exp2f(mrun[r] - mn); // first iter: exp2(-inf)=0
      mrun[r] = mn;
      float acc = 0.0f;
#pragma unroll
      for (int kvt = 0; kvt < 4; ++kvt) {
        p[kvt][r] = exp2f(fmaf(s[kvt][r], cs, -mn));
        acc += p[kvt][r];
      }
      rs[r] = acc;
    }
#pragma unroll
    for (int off = 1; off <= 8; off <<= 1)
#pragma unroll
      for (int r = 0; r < 4; ++r) rs[r] += __shfl_xor(rs[r], off);
#pragma unroll
    for (int r = 0; r < 4; ++r) lrun[r] = lrun[r] * corr[r] + rs[r];
#pragma unroll
    for (int dt = 0; dt < 4; ++dt)
#pragma unroll
      for (int r = 0; r < 4; ++r) o[dt][r] *= corr[r];

    // P -> LDS (XOR swizzle: byte ^= (row&7)<<4 ; kills 16-way read conflict)
#pragma unroll
    for (int kvt = 0; kvt < 4; ++kvt)
#pragma unroll
      for (int r = 0; r < 4; ++r) {
        int row = 4 * lg + r;
        int byte = (row * 128 + (kvt * 16 + lc) * 2) ^ ((row & 7) << 4);
        *(__hip_bfloat16*)&Plds[w][byte] = __float2bfloat16(p[kvt][r]);
      }
    __syncthreads(); // cross-lane visibility of P within the block

    short8 pa0 = *(const short8*)&Plds[w][(lc * 128 + 16 * lg) ^ ((lc & 7) << 4)];
    short8 pa1 =
        *(const short8*)&Plds[w][(lc * 128 + 64 + 16 * lg) ^ ((lc & 7) << 4)];
#pragma unroll
    for (int dt = 0; dt < 4; ++dt) {
      short8 v0 =
          *(const short8*)(Vp + (size_t)(dt * 16 + lc) * SEQ + kv0 + 8 * lg);
      short8 v1 = *(const short8*)(Vp + (size_t)(dt * 16 + lc) * SEQ + kv0 +
                                   32 + 8 * lg);
      o[dt] = __builtin_amdgcn_mfma_f32_16x16x32_bf16(pa0, v0, o[dt], 0, 0, 0);
      o[dt] = __builtin_amdgcn_mfma_f32_16x16x32_bf16(pa1, v1, o[dt], 0, 0, 0);
    }
    __syncthreads();
  }

  // normalize + store attn output as bf16 [8192][1024] (row=b*L+l, col=h*64+d)
#pragma unroll
  for (int r = 0; r < 4; ++r) {
    float rinv = 1.0f / lrun[r];
#pragma unroll
    for (int dt = 0; dt < 4; ++dt) {
      float val = o[dt][r] * rinv;
      AO[(size_t)(b * SEQ + q0 + 4 * lg + r) * 1024 + h * 64 + dt * 16 + lc] =
          __float2bfloat16(val);
    }
  }
}

// ---------------------------------------------------------------- launch
extern "C" void kernel_launch(void* const* d_in, const int* in_sizes, int n_in,
                              void* d_out, int out_size, void* d_ws,
                              size_t ws_size, hipStream_t stream) {
  const float* x = (const float*)d_in[0];
  const float* wq = (const float*)d_in[1];
  const float* bq = (const float*)d_in[2];
  const float* wk = (const float*)d_in[3];
  const float* bk = (const float*)d_in[4];
  const float* wv = (const float*)d_in[5];
  const float* bv = (const float*)d_in[6];
  const float* wo = (const float*)d_in[7];
  const float* bo = (const float*)d_in[8];
  float* out = (float*)d_out;
  char* ws = (char*)d_ws;

  // workspace layout (72 MB total)
  __hip_bfloat16* XB = (__hip_bfloat16*)(ws);                  // 16 MB x bf16
  __hip_bfloat16* WT = (__hip_bfloat16*)(ws + (16ull << 20));  // 6 MB WqkvT
  __hip_bfloat16* WOT = (__hip_bfloat16*)(ws + (22ull << 20)); // 2 MB WoT
  __hip_bfloat16* QB = (__hip_bfloat16*)(ws + (24ull << 20));  // 16 MB
  __hip_bfloat16* KB = (__hip_bfloat16*)(ws + (40ull << 20));  // 16 MB
  __hip_bfloat16* VTB = (__hip_bfloat16*)(ws + (56ull << 20)); // 16 MB
  __hip_bfloat16* AO = XB; // reuse: x(bf16) dead after GEMM1

  convert_f32_bf16<<<2048, 256, 0, stream>>>(x, XB, TOK * HIDDEN / 4);
  transpose_to_bf16<<<dim3(16, 16), 256, 0, stream>>>(wq, WT);
  transpose_to_bf16<<<dim3(16, 16), 256, 0, stream>>>(wk, WT + 1024 * 1024);
  transpose_to_bf16<<<dim3(16, 16), 256, 0, stream>>>(wv, WT + 2 * 1024 * 1024);
  transpose_to_bf16<<<dim3(16, 16), 256, 0, stream>>>(wo, WOT);

  // QKV: C[8192,3072] with fused bias + scatter (V transposed)
  gemm128<1, 1024><<<dim3(64, 24), 256, 0, stream>>>(
      XB, WT, nullptr, nullptr, bq, bk, bv, QB, KB, VTB);

  attn64<<<dim3(32, 64), 256, 0, stream>>>(QB, KB, VTB, AO);

  // out = AO @ WoT + bo  (fp32 out)
  gemm128<0, 1024><<<dim3(64, 8), 256, 0, stream>>>(
      AO, WOT, out, bo, nullptr, nullptr, nullptr, nullptr, nullptr, nullptr);
}

// Round 2
// 693.048 us; speedup vs baseline: 1.0535x; 1.0535x over previous
//
#include <hip/hip_runtime.h>
#include <hip/hip_bf16.h>
#include <cstdint>

// MHA fwd: B=4, L=2048, HIDDEN=1024, HEADS=16, HEAD_DIM=64. fp32 in/out,
// bf16 MFMA internally (fp32 accum everywhere).
#define HIDDEN 1024
#define HEADS 16
#define HEAD_DIM 64
#define BATCH 4
#define SEQ 2048
#define TOK (BATCH * SEQ) /* 8192 */

typedef __attribute__((ext_vector_type(8))) short short8; // 8 bf16 (4 VGPRs)
typedef __attribute__((ext_vector_type(4))) float f32x4;

__device__ __forceinline__ void gload_lds16(const void* g, void* s) {
  // global -> LDS direct, 16B/lane; LDS dest = wave-uniform base + lane*16
  __builtin_amdgcn_global_load_lds(
      (const __attribute__((address_space(1))) void*)g,
      (__attribute__((address_space(3))) void*)s, 16, 0, 0);
}

__device__ __forceinline__ unsigned short f2bf(float x) {
  union { __hip_bfloat16 h; unsigned short u; } c;
  c.h = __float2bfloat16(x);
  return c.u;
}

// ---------------------------------------------------------------- conversions
__global__ __launch_bounds__(256) void convert_f32_bf16(
    const float* __restrict__ in, __hip_bfloat16* __restrict__ out, int n4) {
  int idx = blockIdx.x * blockDim.x + threadIdx.x;
  int stride = gridDim.x * blockDim.x;
  for (int i = idx; i < n4; i += stride) {
    float4 v = ((const float4*)in)[i];
    union { ushort4 u; __hip_bfloat16 h[4]; } r;
    r.h[0] = __float2bfloat16(v.x);
    r.h[1] = __float2bfloat16(v.y);
    r.h[2] = __float2bfloat16(v.z);
    r.h[3] = __float2bfloat16(v.w);
    ((ushort4*)out)[i] = r.u;
  }
}

// W [K=1024][N=1024] fp32 -> Wt [N][K] bf16 (64x64 LDS tile transpose)
__global__ __launch_bounds__(256) void transpose_to_bf16(
    const float* __restrict__ in, __hip_bfloat16* __restrict__ out) {
  __shared__ __hip_bfloat16 t[64][65];
  const int tx = threadIdx.x & 63;
  const int ty = threadIdx.x >> 6; // 0..3
  const int k0 = blockIdx.y * 64;
  const int n0 = blockIdx.x * 64;
#pragma unroll
  for (int i = 0; i < 16; ++i) {
    int r = i * 4 + ty;
    t[r][tx] = __float2bfloat16(in[(size_t)(k0 + r) * 1024 + n0 + tx]);
  }
  __syncthreads();
#pragma unroll
  for (int i = 0; i < 16; ++i) {
    int r = i * 4 + ty;
    out[(size_t)(n0 + r) * 1024 + k0 + tx] = t[tx][r];
  }
}

// ---------------------------------------------------------------- GEMM (m97)
// C[M,N] = A[M,K](bf16) @ Bt[N,K](bf16)^T ; 128x128 tile, BK=32, 4 waves.
// EPI==0: C = acc + bias[n] -> fp32 Cout (ld 1024)
// EPI==1: fused QKV epilogue: n in [0,1024)->Q, [1024,2048)->K  ([B,H,L,D] bf16)
//                             [2048,3072)->V transposed ([B,H,D,L] bf16)
template <int EPI, int KDIM>
__global__ __launch_bounds__(256) void gemm128(
    const __hip_bfloat16* __restrict__ A, const __hip_bfloat16* __restrict__ Bt,
    float* __restrict__ Cout, const float* __restrict__ bias,
    const float* __restrict__ bq, const float* __restrict__ bk,
    const float* __restrict__ bv, __hip_bfloat16* __restrict__ Qb,
    __hip_bfloat16* __restrict__ Kb, __hip_bfloat16* __restrict__ VTb) {
  __shared__ __hip_bfloat16 As[128 * 32];
  __shared__ __hip_bfloat16 Bs[128 * 32];
  const int tid = threadIdx.x;
  const int w = tid >> 6, l = tid & 63;
  const int lc = l & 15, lg = l >> 4;
  const int wr = w >> 1, wc = w & 1;
  const int bm0 = blockIdx.x * 128;
  const int bn0 = blockIdx.y * 128;
  const int lrow = l >> 2;      // row within 16-row chunk
  const int lk = (l & 3) * 8;   // k element offset within 32

  f32x4 acc[4][4] = {};

#pragma unroll 1
  for (int kt = 0; kt < KDIM; kt += 32) {
    if (w < 2) { // waves 0,1 stage A (rows 0..127)
#pragma unroll
      for (int i = 0; i < 4; ++i) {
        int rloc = w * 64 + i * 16;
        const __hip_bfloat16* src =
            A + (size_t)(bm0 + rloc + lrow) * KDIM + kt + lk;
        gload_lds16(src, &As[rloc * 32]);
      }
    } else { // waves 2,3 stage B
#pragma unroll
      for (int i = 0; i < 4; ++i) {
        int rloc = (w - 2) * 64 + i * 16;
        const __hip_bfloat16* src =
            Bt + (size_t)(bn0 + rloc + lrow) * KDIM + kt + lk;
        gload_lds16(src, &Bs[rloc * 32]);
      }
    }
    __syncthreads();
    short8 af[4], bf[4];
#pragma unroll
    for (int mt = 0; mt < 4; ++mt)
      af[mt] = *(const short8*)&As[(wr * 64 + mt * 16 + lc) * 32 + 8 * lg];
#pragma unroll
    for (int nt = 0; nt < 4; ++nt)
      bf[nt] = *(const short8*)&Bs[(wc * 64 + nt * 16 + lc) * 32 + 8 * lg];
#pragma unroll
    for (int mt = 0; mt < 4; ++mt)
#pragma unroll
      for (int nt = 0; nt < 4; ++nt)
        acc[mt][nt] = __builtin_amdgcn_mfma_f32_16x16x32_bf16(
            af[mt], bf[nt], acc[mt][nt], 0, 0, 0);
    __syncthreads();
  }

#pragma unroll
  for (int mt = 0; mt < 4; ++mt) {
#pragma unroll
    for (int nt = 0; nt < 4; ++nt) {
#pragma unroll
      for (int r = 0; r < 4; ++r) {
        int m = bm0 + wr * 64 + mt * 16 + 4 * lg + r;
        int n = bn0 + wc * 64 + nt * 16 + lc;
        float v = acc[mt][nt][r];
        if (EPI == 0) {
          Cout[(size_t)m * 1024 + n] = v + bias[n];
        } else {
          int proj = n >> 10, win = n & 1023, h = win >> 6, d = win & 63;
          const float* bp = (proj == 0) ? bq : ((proj == 1) ? bk : bv);
          __hip_bfloat16 hv = __float2bfloat16(v + bp[win]);
          int b = m >> 11, lq = m & 2047;
          if (proj == 0)
            Qb[((size_t)(b * 16 + h) * 2048 + lq) * 64 + d] = hv;
          else if (proj == 1)
            Kb[((size_t)(b * 16 + h) * 2048 + lq) * 64 + d] = hv;
          else
            VTb[((size_t)(b * 16 + h) * 64 + d) * 2048 + lq] = hv;
        }
      }
    }
  }
}

// ---------------------------------------------------------------- attention
// 4 independent waves/block (NO __syncthreads — per-wave LDS strips only).
// Swapped-operand flash attention:
//   S^T[kv][q] = mfma(A=K, B=Q)  -> lane holds q = lane&15 (scalar m/l state)
//   O^T[d][q]  = mfma(A=V^T, B=P) -> corr/lrun apply as per-lane scalars
// P round-trips through a per-wave XOR-swizzled LDS strip (b64 writes, b128
// reads, 8 lanes/16B-granule = structural optimum). K frags double-buffered
// across kv iterations; V loads issued at iteration top (hidden by softmax).
__global__ __launch_bounds__(256) void attn64(
    const __hip_bfloat16* __restrict__ Qb, const __hip_bfloat16* __restrict__ Kb,
    const __hip_bfloat16* __restrict__ VTb, __hip_bfloat16* __restrict__ AO) {
  __shared__ __align__(16) char Plds[4][2048]; // per-wave [16 q][64 kv] bf16
  const int tid = threadIdx.x;
  const int w = tid >> 6, l = tid & 63;
  const int lc = l & 15, lg = l >> 4;
  const int bh = blockIdx.y; // 0..63
  const int qb = blockIdx.x; // 0..31
  const int b = bh >> 4, h = bh & 15;

  const __hip_bfloat16* Qp = Qb + (size_t)bh * SEQ * 64;
  const __hip_bfloat16* Kp = Kb + (size_t)bh * SEQ * 64;
  const __hip_bfloat16* Vp = VTb + (size_t)bh * 64 * SEQ;

  const int q0 = qb * 64 + w * 16;
  // Q as B-operand: col = q = lc, k = d = 8*lg + i
  short8 qf0 = *(const short8*)(Qp + (q0 + lc) * 64 + 8 * lg);
  short8 qf1 = *(const short8*)(Qp + (q0 + lc) * 64 + 32 + 8 * lg);

  f32x4 o[4] = {};
  float mrun = -INFINITY, lrun = 0.0f;
  const float cs = 0.125f * 1.44269504088896f; // scale * log2(e)

  char* myP = Plds[w];
  const int swz = (lc & 7) << 4;
  // precomputed LDS byte addresses
  int wr_addr[4], rd0_addr, rd1_addr;
#pragma unroll
  for (int kvt = 0; kvt < 4; ++kvt)
    wr_addr[kvt] = (lc * 128 + 32 * kvt + 8 * lg) ^ swz;
  rd0_addr = (lc * 128 + 16 * lg) ^ swz;
  rd1_addr = (lc * 128 + 64 + 16 * lg) ^ swz;

  // K prefetch (A-operand: row = kv = 16*kvt + lc, k = d)
  short8 kf0[4], kf1[4];
#pragma unroll
  for (int kvt = 0; kvt < 4; ++kvt) {
    kf0[kvt] = *(const short8*)(Kp + (kvt * 16 + lc) * 64 + 8 * lg);
    kf1[kvt] = *(const short8*)(Kp + (kvt * 16 + lc) * 64 + 32 + 8 * lg);
  }

#pragma unroll 1
  for (int kv0 = 0; kv0 < SEQ; kv0 += 64) {
    // V loads for this iter (A-operand of PV: row = d = 16*dt + lc, k = kv)
    short8 vf0[4], vf1[4];
#pragma unroll
    for (int dt = 0; dt < 4; ++dt) {
      vf0[dt] = *(const short8*)(Vp + (size_t)(dt * 16 + lc) * SEQ + kv0 + 8 * lg);
      vf1[dt] =
          *(const short8*)(Vp + (size_t)(dt * 16 + lc) * SEQ + kv0 + 32 + 8 * lg);
    }

    // S^T = K @ Q^T : s[kvt] reg r -> (q = lc, kv = kv0 + 16*kvt + 4*lg + r)
    f32x4 s[4];
#pragma unroll
    for (int kvt = 0; kvt < 4; ++kvt) {
      f32x4 z = {};
      z = __builtin_amdgcn_mfma_f32_16x16x32_bf16(kf0[kvt], qf0, z, 0, 0, 0);
      s[kvt] = __builtin_amdgcn_mfma_f32_16x16x32_bf16(kf1[kvt], qf1, z, 0, 0, 0);
    }

    // prefetch next-iter K (wraps harmlessly on last iter; values unused)
    const int kvn = (kv0 + 64) & (SEQ - 1);
    short8 kn0[4], kn1[4];
#pragma unroll
    for (int kvt = 0; kvt < 4; ++kvt) {
      kn0[kvt] = *(const short8*)(Kp + (kvn + kvt * 16 + lc) * 64 + 8 * lg);
      kn1[kvt] = *(const short8*)(Kp + (kvn + kvt * 16 + lc) * 64 + 32 + 8 * lg);
    }

    // ---- softmax (per-lane scalar state; all 16 S values share q = lc)
    float t0 = fmaxf(fmaxf(s[0][0], s[0][1]), fmaxf(s[0][2], s[0][3]));
    float t1 = fmaxf(fmaxf(s[1][0], s[1][1]), fmaxf(s[1][2], s[1][3]));
    float t2 = fmaxf(fmaxf(s[2][0], s[2][1]), fmaxf(s[2][2], s[2][3]));
    float t3 = fmaxf(fmaxf(s[3][0], s[3][1]), fmaxf(s[3][2], s[3][3]));
    float t = fmaxf(fmaxf(t0, t1), fmaxf(t2, t3));
    t = fmaxf(t, __shfl_xor(t, 16));
    t = fmaxf(t, __shfl_xor(t, 32));

    float mn = fmaxf(mrun, t * cs);
    float corr = exp2f(mrun - mn); // first iter: exp2(-inf) = 0
    mrun = mn;

    float p[4][4];
    float rs = 0.0f;
#pragma unroll
    for (int kvt = 0; kvt < 4; ++kvt)
#pragma unroll
      for (int r = 0; r < 4; ++r) {
        p[kvt][r] = exp2f(fmaf(s[kvt][r], cs, -mn));
        rs += p[kvt][r];
      }
    rs += __shfl_xor(rs, 16);
    rs += __shfl_xor(rs, 32);
    lrun = lrun * corr + rs;

    // ---- P -> LDS (packed b64 writes, XOR swizzle)
#pragma unroll
    for (int kvt = 0; kvt < 4; ++kvt) {
      ushort4 pk;
      pk.x = f2bf(p[kvt][0]);
      pk.y = f2bf(p[kvt][1]);
      pk.z = f2bf(p[kvt][2]);
      pk.w = f2bf(p[kvt][3]);
      *(ushort4*)(myP + wr_addr[kvt]) = pk;
    }
    asm volatile("s_waitcnt lgkmcnt(0)" ::: "memory");
    __builtin_amdgcn_sched_barrier(0);
    // P as B-operand: col = q = lc, k = kv = 8*lg + i (+32 for frag 1)
    short8 pb0 = *(const short8*)(myP + rd0_addr);
    short8 pb1 = *(const short8*)(myP + rd1_addr);

    // ---- rescale + PV:  O^T[d][q] accumulate
#pragma unroll
    for (int dt = 0; dt < 4; ++dt) {
#pragma unroll
      for (int r = 0; r < 4; ++r) o[dt][r] *= corr;
      o[dt] = __builtin_amdgcn_mfma_f32_16x16x32_bf16(vf0[dt], pb0, o[dt], 0, 0, 0);
      o[dt] = __builtin_amdgcn_mfma_f32_16x16x32_bf16(vf1[dt], pb1, o[dt], 0, 0, 0);
    }

#pragma unroll
    for (int kvt = 0; kvt < 4; ++kvt) {
      kf0[kvt] = kn0[kvt];
      kf1[kvt] = kn1[kvt];
    }
  }

  // normalize + store: lane holds q = q0 + lc, d = 16*dt + 4*lg + r
  float rinv = 1.0f / lrun;
  const size_t row = (size_t)(b * SEQ + q0 + lc) * 1024 + h * 64;
#pragma unroll
  for (int dt = 0; dt < 4; ++dt) {
    ushort4 ok;
    ok.x = f2bf(o[dt][0] * rinv);
    ok.y = f2bf(o[dt][1] * rinv);
    ok.z = f2bf(o[dt][2] * rinv);
    ok.w = f2bf(o[dt][3] * rinv);
    *(ushort4*)(AO + row + 16 * dt + 4 * lg) = ok;
  }
}

// ---------------------------------------------------------------- launch
extern "C" void kernel_launch(void* const* d_in, const int* in_sizes, int n_in,
                              void* d_out, int out_size, void* d_ws,
                              size_t ws_size, hipStream_t stream) {
  const float* x = (const float*)d_in[0];
  const float* wq = (const float*)d_in[1];
  const float* bq = (const float*)d_in[2];
  const float* wk = (const float*)d_in[3];
  const float* bk = (const float*)d_in[4];
  const float* wv = (const float*)d_in[5];
  const float* bv = (const float*)d_in[6];
  const float* wo = (const float*)d_in[7];
  const float* bo = (const float*)d_in[8];
  float* out = (float*)d_out;
  char* ws = (char*)d_ws;

  // workspace layout (72 MB total)
  __hip_bfloat16* XB = (__hip_bfloat16*)(ws);                  // 16 MB x bf16
  __hip_bfloat16* WT = (__hip_bfloat16*)(ws + (16ull << 20));  // 6 MB WqkvT
  __hip_bfloat16* WOT = (__hip_bfloat16*)(ws + (22ull << 20)); // 2 MB WoT
  __hip_bfloat16* QB = (__hip_bfloat16*)(ws + (24ull << 20));  // 16 MB
  __hip_bfloat16* KB = (__hip_bfloat16*)(ws + (40ull << 20));  // 16 MB
  __hip_bfloat16* VTB = (__hip_bfloat16*)(ws + (56ull << 20)); // 16 MB
  __hip_bfloat16* AO = XB; // reuse: x(bf16) dead after GEMM1

  convert_f32_bf16<<<2048, 256, 0, stream>>>(x, XB, TOK * HIDDEN / 4);
  transpose_to_bf16<<<dim3(16, 16), 256, 0, stream>>>(wq, WT);
  transpose_to_bf16<<<dim3(16, 16), 256, 0, stream>>>(wk, WT + 1024 * 1024);
  transpose_to_bf16<<<dim3(16, 16), 256, 0, stream>>>(wv, WT + 2 * 1024 * 1024);
  transpose_to_bf16<<<dim3(16, 16), 256, 0, stream>>>(wo, WOT);

  // QKV: C[8192,3072] with fused bias + scatter (V transposed)
  gemm128<1, 1024><<<dim3(64, 24), 256, 0, stream>>>(
      XB, WT, nullptr, nullptr, bq, bk, bv, QB, KB, VTB);

  attn64<<<dim3(32, 64), 256, 0, stream>>>(QB, KB, VTB, AO);

  // out = AO @ WoT + bo  (fp32 out)
  gemm128<0, 1024><<<dim3(64, 8), 256, 0, stream>>>(
      AO, WOT, out, bo, nullptr, nullptr, nullptr, nullptr, nullptr, nullptr);
}

// Round 4
// 368.624 us; speedup vs baseline: 1.9806x; 1.8801x over previous
//
#include <hip/hip_runtime.h>
#include <hip/hip_bf16.h>
#include <cstdint>

// MHA fwd: B=4, L=2048, HIDDEN=1024, HEADS=16, HEAD_DIM=64. fp32 in/out,
// bf16 MFMA internally (fp32 accum everywhere).
#define HIDDEN 1024
#define HEADS 16
#define HEAD_DIM 64
#define BATCH 4
#define SEQ 2048
#define TOK (BATCH * SEQ) /* 8192 */

typedef __attribute__((ext_vector_type(8))) short short8;   // 8 bf16 (4 VGPRs)
typedef __attribute__((ext_vector_type(4))) float f32x4;
typedef __attribute__((ext_vector_type(16))) float f32x16;

__device__ __forceinline__ void gload_lds16(const void* g, void* s) {
  // global -> LDS direct, 16B/lane; LDS dest = wave-uniform base + lane*16
  __builtin_amdgcn_global_load_lds(
      (const __attribute__((address_space(1))) void*)g,
      (__attribute__((address_space(3))) void*)s, 16, 0, 0);
}

__device__ __forceinline__ unsigned short f2bf(float x) {
  union { __hip_bfloat16 h; unsigned short u; } c;
  c.h = __float2bfloat16(x);
  return c.u;
}

// ---------------------------------------------------------------- conversions
__global__ __launch_bounds__(256) void convert_f32_bf16(
    const float* __restrict__ in, __hip_bfloat16* __restrict__ out, int n4) {
  int idx = blockIdx.x * blockDim.x + threadIdx.x;
  int stride = gridDim.x * blockDim.x;
  for (int i = idx; i < n4; i += stride) {
    float4 v = ((const float4*)in)[i];
    union { ushort4 u; __hip_bfloat16 h[4]; } r;
    r.h[0] = __float2bfloat16(v.x);
    r.h[1] = __float2bfloat16(v.y);
    r.h[2] = __float2bfloat16(v.z);
    r.h[3] = __float2bfloat16(v.w);
    ((ushort4*)out)[i] = r.u;
  }
}

// W [K=1024][N=1024] fp32 -> Wt [N][K] bf16 (64x64 LDS tile transpose)
__global__ __launch_bounds__(256) void transpose_to_bf16(
    const float* __restrict__ in, __hip_bfloat16* __restrict__ out) {
  __shared__ __hip_bfloat16 t[64][65];
  const int tx = threadIdx.x & 63;
  const int ty = threadIdx.x >> 6; // 0..3
  const int k0 = blockIdx.y * 64;
  const int n0 = blockIdx.x * 64;
#pragma unroll
  for (int i = 0; i < 16; ++i) {
    int r = i * 4 + ty;
    t[r][tx] = __float2bfloat16(in[(size_t)(k0 + r) * 1024 + n0 + tx]);
  }
  __syncthreads();
#pragma unroll
  for (int i = 0; i < 16; ++i) {
    int r = i * 4 + ty;
    out[(size_t)(n0 + r) * 1024 + k0 + tx] = t[tx][r];
  }
}

// ---------------------------------------------------------------- GEMM (m97)
// C[M,N] = A[M,K](bf16) @ Bt[N,K](bf16)^T ; 128x128 tile, BK=32, 4 waves.
// EPI==0: C = acc + bias[n] -> fp32 Cout (ld 1024)
// EPI==1: fused QKV epilogue: n in [0,1024)->Q, [1024,2048)->K  ([B,H,L,D] bf16)
//                             [2048,3072)->V transposed ([B,H,D,L] bf16)
template <int EPI, int KDIM>
__global__ __launch_bounds__(256) void gemm128(
    const __hip_bfloat16* __restrict__ A, const __hip_bfloat16* __restrict__ Bt,
    float* __restrict__ Cout, const float* __restrict__ bias,
    const float* __restrict__ bq, const float* __restrict__ bk,
    const float* __restrict__ bv, __hip_bfloat16* __restrict__ Qb,
    __hip_bfloat16* __restrict__ Kb, __hip_bfloat16* __restrict__ VTb) {
  __shared__ __hip_bfloat16 As[128 * 32];
  __shared__ __hip_bfloat16 Bs[128 * 32];
  const int tid = threadIdx.x;
  const int w = tid >> 6, l = tid & 63;
  const int lc = l & 15, lg = l >> 4;
  const int wr = w >> 1, wc = w & 1;
  const int bm0 = blockIdx.x * 128;
  const int bn0 = blockIdx.y * 128;
  const int lrow = l >> 2;      // row within 16-row chunk
  const int lk = (l & 3) * 8;   // k element offset within 32

  f32x4 acc[4][4] = {};

#pragma unroll 1
  for (int kt = 0; kt < KDIM; kt += 32) {
    if (w < 2) { // waves 0,1 stage A (rows 0..127)
#pragma unroll
      for (int i = 0; i < 4; ++i) {
        int rloc = w * 64 + i * 16;
        const __hip_bfloat16* src =
            A + (size_t)(bm0 + rloc + lrow) * KDIM + kt + lk;
        gload_lds16(src, &As[rloc * 32]);
      }
    } else { // waves 2,3 stage B
#pragma unroll
      for (int i = 0; i < 4; ++i) {
        int rloc = (w - 2) * 64 + i * 16;
        const __hip_bfloat16* src =
            Bt + (size_t)(bn0 + rloc + lrow) * KDIM + kt + lk;
        gload_lds16(src, &Bs[rloc * 32]);
      }
    }
    __syncthreads();
    short8 af[4], bf[4];
#pragma unroll
    for (int mt = 0; mt < 4; ++mt)
      af[mt] = *(const short8*)&As[(wr * 64 + mt * 16 + lc) * 32 + 8 * lg];
#pragma unroll
    for (int nt = 0; nt < 4; ++nt)
      bf[nt] = *(const short8*)&Bs[(wc * 64 + nt * 16 + lc) * 32 + 8 * lg];
#pragma unroll
    for (int mt = 0; mt < 4; ++mt)
#pragma unroll
      for (int nt = 0; nt < 4; ++nt)
        acc[mt][nt] = __builtin_amdgcn_mfma_f32_16x16x32_bf16(
            af[mt], bf[nt], acc[mt][nt], 0, 0, 0);
    __syncthreads();
  }

#pragma unroll
  for (int mt = 0; mt < 4; ++mt) {
#pragma unroll
    for (int nt = 0; nt < 4; ++nt) {
#pragma unroll
      for (int r = 0; r < 4; ++r) {
        int m = bm0 + wr * 64 + mt * 16 + 4 * lg + r;
        int n = bn0 + wc * 64 + nt * 16 + lc;
        float v = acc[mt][nt][r];
        if (EPI == 0) {
          Cout[(size_t)m * 1024 + n] = v + bias[n];
        } else {
          int proj = n >> 10, win = n & 1023, h = win >> 6, d = win & 63;
          const float* bp = (proj == 0) ? bq : ((proj == 1) ? bk : bv);
          __hip_bfloat16 hv = __float2bfloat16(v + bp[win]);
          int b = m >> 11, lq = m & 2047;
          if (proj == 0)
            Qb[((size_t)(b * 16 + h) * 2048 + lq) * 64 + d] = hv;
          else if (proj == 1)
            Kb[((size_t)(b * 16 + h) * 2048 + lq) * 64 + d] = hv;
          else
            VTb[((size_t)(b * 16 + h) * 64 + d) * 2048 + lq] = hv;
        }
      }
    }
  }
}

// ---------------------------------------------------------------- attention
// 4 warps x 32 q-rows (QBLK=128), KVBLK=64, 32x32x16 MFMA, swapped operands.
//   S^T tile = mfma(A=K[32kv x 16d], B=Q[16d x 32q]) -> lane: q = l&31,
//     kv = crow(r,hi) = (r&3) + 8*(r>>2) + 4*hi  (per 32-kv tile)
//   PV: O^T tile = mfma(A=V^T[32d x 16kv], B=P[16kv x 32q]) with kv-slot
//     permutation pi(ks,hi,j) = 16ks + 8*(j>>2) + 4*hi + (j&3) applied to BOTH
//     P's k-slots (pure in-lane regs!) and V^T ds_read addresses -> no
//     cross-lane P exchange, no P LDS round-trip.
// K/V tiles staged in LDS (XOR-swizzled, rule-21: linear dest + inverse-
// swizzled global src), double-buffered, shared by all 4 warps. One
// __syncthreads per kv-iter (2-phase).
__global__ __launch_bounds__(256, 2) void attn32(
    const __hip_bfloat16* __restrict__ Qb, const __hip_bfloat16* __restrict__ Kb,
    const __hip_bfloat16* __restrict__ VTb, __hip_bfloat16* __restrict__ AO) {
  __shared__ __align__(16) char lds[2][2][8192]; // [buf][K=0/V=1][64 rows x 128B]
  const int tid = threadIdx.x;
  const int w = tid >> 6, l = tid & 63;
  const int q32 = l & 31; // q col / kv row / d row within a 32-tile
  const int hi = l >> 5;
  const int bh = blockIdx.y; // 0..63
  const int qb = blockIdx.x; // 0..15
  const int b = bh >> 4, h = bh & 15;

  const __hip_bfloat16* Qp = Qb + (size_t)bh * SEQ * 64;
  const char* Kg = (const char*)(Kb + (size_t)bh * SEQ * 64);
  const char* Vg = (const char*)(VTb + (size_t)bh * 64 * SEQ);

  // ---- Q fragments (B-operand): col = q = q32, k = d = ds*16 + 8*hi + j
  const int q0w = qb * 128 + w * 32;
  short8 qf[4];
#pragma unroll
  for (int ds = 0; ds < 4; ++ds)
    qf[ds] = *(const short8*)(Qp + (size_t)(q0w + q32) * 64 + ds * 16 + 8 * hi);

  // ---- staging addressing: instr i covers LDS rows i*8..i*8+7;
  // lane l -> row r = i*8 + (l>>3), 16B chunk c' = 16*(l&7);
  // global col byte = c' ^ ((r&7)<<4)   (inverse of read-side swizzle)
  const int srow = l >> 3;                       // == r&7
  const int scol = (16 * (l & 7)) ^ (srow << 4); // 0..127, 16B aligned
  const int i0 = 2 * w, i1 = 2 * w + 1;          // this warp's 2 stage rows-of-8

#define STAGE_KV(buf, kv0)                                                   \
  {                                                                          \
    gload_lds16(Kg + (size_t)((kv0) + i0 * 8 + srow) * 128 + scol,           \
                &lds[buf][0][i0 * 1024]);                                    \
    gload_lds16(Kg + (size_t)((kv0) + i1 * 8 + srow) * 128 + scol,           \
                &lds[buf][0][i1 * 1024]);                                    \
    gload_lds16(Vg + (size_t)(i0 * 8 + srow) * (SEQ * 2) +                   \
                    (size_t)(kv0) * 2 + scol,                                \
                &lds[buf][1][i0 * 1024]);                                    \
    gload_lds16(Vg + (size_t)(i1 * 8 + srow) * (SEQ * 2) +                   \
                    (size_t)(kv0) * 2 + scol,                                \
                &lds[buf][1][i1 * 1024]);                                    \
  }

  STAGE_KV(0, 0);

  f32x16 o0 = {}, o1 = {}; // O^T tiles dt=0,1: col=q32, row d = crow(r,hi)+32dt
  float mrun = -INFINITY, lrun = 0.0f;
  const float cs = 0.125f * 1.44269504088896f; // scale * log2(e)
  const int swz = (q32 & 7) << 4;              // read-side XOR swizzle

#pragma unroll 1
  for (int it = 0; it < 32; ++it) {
    const int kv0 = it * 64;
    const int cur = it & 1;
    __syncthreads(); // drains vmcnt+lgkm: buf[cur] staged, buf[cur^1] free
    if (it < 31) STAGE_KV(cur ^ 1, kv0 + 64);

    // ---- QK^T: 2 kv-tiles x 4 d-slices
    const char* Kt = lds[cur][0];
    f32x16 s0 = {}, s1 = {};
#pragma unroll
    for (int ds = 0; ds < 4; ++ds) {
      const int c = (32 * ds + 16 * hi) ^ swz;
      short8 k0 = *(const short8*)(Kt + q32 * 128 + c);
      short8 k1 = *(const short8*)(Kt + (32 + q32) * 128 + c);
      s0 = __builtin_amdgcn_mfma_f32_32x32x16_bf16(k0, qf[ds], s0, 0, 0, 0);
      s1 = __builtin_amdgcn_mfma_f32_32x32x16_bf16(k1, qf[ds], s1, 0, 0, 0);
    }

    // ---- softmax: in-lane tree over 32 values + one cross-lane (l^32)
    float tm[8];
#pragma unroll
    for (int i = 0; i < 8; ++i)
      tm[i] = fmaxf(fmaxf(s0[2 * i], s0[2 * i + 1]),
                    fmaxf(s1[2 * i], s1[2 * i + 1]));
    float t = fmaxf(fmaxf(fmaxf(tm[0], tm[1]), fmaxf(tm[2], tm[3])),
                    fmaxf(fmaxf(tm[4], tm[5]), fmaxf(tm[6], tm[7])));
    t = fmaxf(t, __shfl_xor(t, 32));

    const float mn = fmaxf(mrun, t * cs);
    const float corr = exp2f(mrun - mn); // first iter: exp2(-inf) = 0
    mrun = mn;

    float p0[16], p1[16];
    float rs = 0.0f;
#pragma unroll
    for (int i = 0; i < 16; ++i) {
      p0[i] = exp2f(fmaf(s0[i], cs, -mn));
      p1[i] = exp2f(fmaf(s1[i], cs, -mn));
      rs += p0[i] + p1[i];
    }
    rs += __shfl_xor(rs, 32);
    lrun = lrun * corr + rs;

    // ---- P -> bf16 words, all in-lane: for slice ks, B-frag word g packs
    // p_t[base+2g], p_t[base+2g+1] with t = ks>>1, base = 8*(ks&1)
    uint32_t pw[4][4];
#pragma unroll
    for (int ks = 0; ks < 4; ++ks) {
      const int base = 8 * (ks & 1);
#pragma unroll
      for (int g = 0; g < 4; ++g) {
        float lo = (ks < 2) ? p0[base + 2 * g] : p1[base + 2 * g];
        float hp = (ks < 2) ? p0[base + 2 * g + 1] : p1[base + 2 * g + 1];
        pw[ks][g] = (uint32_t)f2bf(lo) | ((uint32_t)f2bf(hp) << 16);
      }
    }

    // ---- rescale O
    o0 *= corr;
    o1 *= corr;

    // ---- PV: A = V^T frag (2 x ds_read_b64, pi-permuted kv), B = P words
    const char* Vt = lds[cur][1];
#pragma unroll
    for (int ks = 0; ks < 4; ++ks) {
      union { short8 v; uint32_t u[4]; } pb;
      pb.u[0] = pw[ks][0];
      pb.u[1] = pw[ks][1];
      pb.u[2] = pw[ks][2];
      pb.u[3] = pw[ks][3];
      const int cA = (32 * ks + 8 * hi) ^ swz;      // kv 16ks+4hi+0..3
      const int cB = (32 * ks + 16 + 8 * hi) ^ swz; // kv 16ks+8+4hi+0..3
      union { short8 v; uint64_t u[2]; } a0, a1;
      a0.u[0] = *(const uint64_t*)(Vt + q32 * 128 + cA);
      a0.u[1] = *(const uint64_t*)(Vt + q32 * 128 + cB);
      a1.u[0] = *(const uint64_t*)(Vt + (32 + q32) * 128 + cA);
      a1.u[1] = *(const uint64_t*)(Vt + (32 + q32) * 128 + cB);
      o0 = __builtin_amdgcn_mfma_f32_32x32x16_bf16(a0.v, pb.v, o0, 0, 0, 0);
      o1 = __builtin_amdgcn_mfma_f32_32x32x16_bf16(a1.v, pb.v, o1, 0, 0, 0);
    }
  }

  // ---- normalize + store: lane q = q0w + q32; d = 32*dt + 8*g + 4*hi + u,
  // regs r = 4g+u of o[dt]
  const float rinv = 1.0f / lrun;
  const size_t orow = (size_t)(b * SEQ + q0w + q32) * 1024 + h * 64;
#pragma unroll
  for (int g = 0; g < 4; ++g) {
    ushort4 c0, c1;
    c0.x = f2bf(o0[4 * g + 0] * rinv);
    c0.y = f2bf(o0[4 * g + 1] * rinv);
    c0.z = f2bf(o0[4 * g + 2] * rinv);
    c0.w = f2bf(o0[4 * g + 3] * rinv);
    c1.x = f2bf(o1[4 * g + 0] * rinv);
    c1.y = f2bf(o1[4 * g + 1] * rinv);
    c1.z = f2bf(o1[4 * g + 2] * rinv);
    c1.w = f2bf(o1[4 * g + 3] * rinv);
    *(ushort4*)(AO + orow + 8 * g + 4 * hi) = c0;
    *(ushort4*)(AO + orow + 32 + 8 * g + 4 * hi) = c1;
  }
#undef STAGE_KV
}

// ---------------------------------------------------------------- launch
extern "C" void kernel_launch(void* const* d_in, const int* in_sizes, int n_in,
                              void* d_out, int out_size, void* d_ws,
                              size_t ws_size, hipStream_t stream) {
  const float* x = (const float*)d_in[0];
  const float* wq = (const float*)d_in[1];
  const float* bq = (const float*)d_in[2];
  const float* wk = (const float*)d_in[3];
  const float* bk = (const float*)d_in[4];
  const float* wv = (const float*)d_in[5];
  const float* bv = (const float*)d_in[6];
  const float* wo = (const float*)d_in[7];
  const float* bo = (const float*)d_in[8];
  float* out = (float*)d_out;
  char* ws = (char*)d_ws;

  // workspace layout (72 MB total)
  __hip_bfloat16* XB = (__hip_bfloat16*)(ws);                  // 16 MB x bf16
  __hip_bfloat16* WT = (__hip_bfloat16*)(ws + (16ull << 20));  // 6 MB WqkvT
  __hip_bfloat16* WOT = (__hip_bfloat16*)(ws + (22ull << 20)); // 2 MB WoT
  __hip_bfloat16* QB = (__hip_bfloat16*)(ws + (24ull << 20));  // 16 MB
  __hip_bfloat16* KB = (__hip_bfloat16*)(ws + (40ull << 20));  // 16 MB
  __hip_bfloat16* VTB = (__hip_bfloat16*)(ws + (56ull << 20)); // 16 MB
  __hip_bfloat16* AO = XB; // reuse: x(bf16) dead after GEMM1

  convert_f32_bf16<<<2048, 256, 0, stream>>>(x, XB, TOK * HIDDEN / 4);
  transpose_to_bf16<<<dim3(16, 16), 256, 0, stream>>>(wq, WT);
  transpose_to_bf16<<<dim3(16, 16), 256, 0, stream>>>(wk, WT + 1024 * 1024);
  transpose_to_bf16<<<dim3(16, 16), 256, 0, stream>>>(wv, WT + 2 * 1024 * 1024);
  transpose_to_bf16<<<dim3(16, 16), 256, 0, stream>>>(wo, WOT);

  // QKV: C[8192,3072] with fused bias + scatter (V transposed)
  gemm128<1, 1024><<<dim3(64, 24), 256, 0, stream>>>(
      XB, WT, nullptr, nullptr, bq, bk, bv, QB, KB, VTB);

  attn32<<<dim3(16, 64), 256, 0, stream>>>(QB, KB, VTB, AO);

  // out = AO @ WoT + bo  (fp32 out)
  gemm128<0, 1024><<<dim3(64, 8), 256, 0, stream>>>(
      AO, WOT, out, bo, nullptr, nullptr, nullptr, nullptr, nullptr, nullptr);
}

// Round 6
// 349.365 us; speedup vs baseline: 2.0898x; 1.0551x over previous
//
#include <hip/hip_runtime.h>
#include <hip/hip_bf16.h>
#include <cstdint>

// MHA fwd: B=4, L=2048, HIDDEN=1024, HEADS=16, HEAD_DIM=64. fp32 in/out,
// bf16 MFMA internally (fp32 accum everywhere).
#define HIDDEN 1024
#define HEADS 16
#define HEAD_DIM 64
#define BATCH 4
#define SEQ 2048
#define TOK (BATCH * SEQ) /* 8192 */

typedef __attribute__((ext_vector_type(8))) short short8;   // 8 bf16 (4 VGPRs)
typedef __attribute__((ext_vector_type(4))) float f32x4;
typedef __attribute__((ext_vector_type(16))) float f32x16;

__device__ __forceinline__ void gload_lds16(const void* g, void* s) {
  // global -> LDS direct, 16B/lane; LDS dest = wave-uniform base + lane*16
  __builtin_amdgcn_global_load_lds(
      (const __attribute__((address_space(1))) void*)g,
      (__attribute__((address_space(3))) void*)s, 16, 0, 0);
}

__device__ __forceinline__ unsigned short f2bf(float x) {
  union { __hip_bfloat16 h; unsigned short u; } c;
  c.h = __float2bfloat16(x);
  return c.u;
}

// HW packed f32->bf16 (RNE), lo = first arg. No builtin on gfx950 (m240) —
// inline asm per T12 recipe. One instr replaces ~6-10 of software RNE.
__device__ __forceinline__ uint32_t cvt_pk_bf16(float lo, float hi) {
  uint32_t r;
  asm("v_cvt_pk_bf16_f32 %0, %1, %2" : "=v"(r) : "v"(lo), "v"(hi));
  return r;
}

// ---------------------------------------------------------------- conversions
__global__ __launch_bounds__(256) void convert_f32_bf16(
    const float* __restrict__ in, __hip_bfloat16* __restrict__ out, int n4) {
  int idx = blockIdx.x * blockDim.x + threadIdx.x;
  int stride = gridDim.x * blockDim.x;
  for (int i = idx; i < n4; i += stride) {
    float4 v = ((const float4*)in)[i];
    union { ushort4 u; __hip_bfloat16 h[4]; } r;
    r.h[0] = __float2bfloat16(v.x);
    r.h[1] = __float2bfloat16(v.y);
    r.h[2] = __float2bfloat16(v.z);
    r.h[3] = __float2bfloat16(v.w);
    ((ushort4*)out)[i] = r.u;
  }
}

// W [K=1024][N=1024] fp32 -> Wt [N][K] bf16 (64x64 LDS tile transpose)
__global__ __launch_bounds__(256) void transpose_to_bf16(
    const float* __restrict__ in, __hip_bfloat16* __restrict__ out) {
  __shared__ __hip_bfloat16 t[64][65];
  const int tx = threadIdx.x & 63;
  const int ty = threadIdx.x >> 6; // 0..3
  const int k0 = blockIdx.y * 64;
  const int n0 = blockIdx.x * 64;
#pragma unroll
  for (int i = 0; i < 16; ++i) {
    int r = i * 4 + ty;
    t[r][tx] = __float2bfloat16(in[(size_t)(k0 + r) * 1024 + n0 + tx]);
  }
  __syncthreads();
#pragma unroll
  for (int i = 0; i < 16; ++i) {
    int r = i * 4 + ty;
    out[(size_t)(n0 + r) * 1024 + k0 + tx] = t[tx][r];
  }
}

// ---------------------------------------------------------------- GEMM (m97)
// C[M,N] = A[M,K](bf16) @ Bt[N,K](bf16)^T ; 128x128 tile, BK=32, 4 waves.
// EPI==0: C = acc + bias[n] -> fp32 Cout (ld 1024)
// EPI==1: fused QKV epilogue: n in [0,1024)->Q, [1024,2048)->K  ([B,H,L,D] bf16)
//                             [2048,3072)->V transposed ([B,H,D,L] bf16)
template <int EPI, int KDIM>
__global__ __launch_bounds__(256) void gemm128(
    const __hip_bfloat16* __restrict__ A, const __hip_bfloat16* __restrict__ Bt,
    float* __restrict__ Cout, const float* __restrict__ bias,
    const float* __restrict__ bq, const float* __restrict__ bk,
    const float* __restrict__ bv, __hip_bfloat16* __restrict__ Qb,
    __hip_bfloat16* __restrict__ Kb, __hip_bfloat16* __restrict__ VTb) {
  __shared__ __hip_bfloat16 As[128 * 32];
  __shared__ __hip_bfloat16 Bs[128 * 32];
  const int tid = threadIdx.x;
  const int w = tid >> 6, l = tid & 63;
  const int lc = l & 15, lg = l >> 4;
  const int wr = w >> 1, wc = w & 1;
  const int bm0 = blockIdx.x * 128;
  const int bn0 = blockIdx.y * 128;
  const int lrow = l >> 2;      // row within 16-row chunk
  const int lk = (l & 3) * 8;   // k element offset within 32

  f32x4 acc[4][4] = {};

#pragma unroll 1
  for (int kt = 0; kt < KDIM; kt += 32) {
    if (w < 2) { // waves 0,1 stage A (rows 0..127)
#pragma unroll
      for (int i = 0; i < 4; ++i) {
        int rloc = w * 64 + i * 16;
        const __hip_bfloat16* src =
            A + (size_t)(bm0 + rloc + lrow) * KDIM + kt + lk;
        gload_lds16(src, &As[rloc * 32]);
      }
    } else { // waves 2,3 stage B
#pragma unroll
      for (int i = 0; i < 4; ++i) {
        int rloc = (w - 2) * 64 + i * 16;
        const __hip_bfloat16* src =
            Bt + (size_t)(bn0 + rloc + lrow) * KDIM + kt + lk;
        gload_lds16(src, &Bs[rloc * 32]);
      }
    }
    __syncthreads();
    short8 af[4], bf[4];
#pragma unroll
    for (int mt = 0; mt < 4; ++mt)
      af[mt] = *(const short8*)&As[(wr * 64 + mt * 16 + lc) * 32 + 8 * lg];
#pragma unroll
    for (int nt = 0; nt < 4; ++nt)
      bf[nt] = *(const short8*)&Bs[(wc * 64 + nt * 16 + lc) * 32 + 8 * lg];
#pragma unroll
    for (int mt = 0; mt < 4; ++mt)
#pragma unroll
      for (int nt = 0; nt < 4; ++nt)
        acc[mt][nt] = __builtin_amdgcn_mfma_f32_16x16x32_bf16(
            af[mt], bf[nt], acc[mt][nt], 0, 0, 0);
    __syncthreads();
  }

#pragma unroll
  for (int mt = 0; mt < 4; ++mt) {
#pragma unroll
    for (int nt = 0; nt < 4; ++nt) {
#pragma unroll
      for (int r = 0; r < 4; ++r) {
        int m = bm0 + wr * 64 + mt * 16 + 4 * lg + r;
        int n = bn0 + wc * 64 + nt * 16 + lc;
        float v = acc[mt][nt][r];
        if (EPI == 0) {
          Cout[(size_t)m * 1024 + n] = v + bias[n];
        } else {
          int proj = n >> 10, win = n & 1023, h = win >> 6, d = win & 63;
          const float* bp = (proj == 0) ? bq : ((proj == 1) ? bk : bv);
          __hip_bfloat16 hv = __float2bfloat16(v + bp[win]);
          int b = m >> 11, lq = m & 2047;
          if (proj == 0)
            Qb[((size_t)(b * 16 + h) * 2048 + lq) * 64 + d] = hv;
          else if (proj == 1)
            Kb[((size_t)(b * 16 + h) * 2048 + lq) * 64 + d] = hv;
          else
            VTb[((size_t)(b * 16 + h) * 64 + d) * 2048 + lq] = hv;
        }
      }
    }
  }
}

// ---------------------------------------------------------------- attention
// 4 warps x 32 q-rows (QBLK=128), KVBLK=64, 32x32x16 MFMA, swapped operands.
//   S^T tile = mfma(A=K[32kv x 16d], B=Q[16d x 32q]) -> lane: q = l&31,
//     kv = crow(r,hi) = (r&3) + 8*(r>>2) + 4*hi  (per 32-kv tile)
//   PV: O^T tile = mfma(A=V^T[32d x 16kv], B=P[16kv x 32q]) with kv-slot
//     permutation pi(ks,hi,j) = 16ks + 8*(j>>2) + 4*hi + (j&3) applied to BOTH
//     P's k-slots (pure in-lane regs!) and V^T ds_read addresses -> no
//     cross-lane P exchange, no P LDS round-trip.
// K/V tiles staged in LDS (XOR-swizzled, rule-21: linear dest + inverse-
// swizzled global src), double-buffered, shared by all 4 warps. One
// __syncthreads per kv-iter (2-phase).
// R5: cvt_pk_bf16 pack (T12), defer-max rescale skip (T13, THR=8 log2),
// max3 tile-max tree (T17), 4 blocks/CU occupancy.
__global__ __launch_bounds__(256, 4) void attn32(
    const __hip_bfloat16* __restrict__ Qb, const __hip_bfloat16* __restrict__ Kb,
    const __hip_bfloat16* __restrict__ VTb, __hip_bfloat16* __restrict__ AO) {
  __shared__ __align__(16) char lds[2][2][8192]; // [buf][K=0/V=1][64 rows x 128B]
  const int tid = threadIdx.x;
  const int w = tid >> 6, l = tid & 63;
  const int q32 = l & 31; // q col / kv row / d row within a 32-tile
  const int hi = l >> 5;
  const int bh = blockIdx.y; // 0..63
  const int qb = blockIdx.x; // 0..15
  const int b = bh >> 4, h = bh & 15;

  const __hip_bfloat16* Qp = Qb + (size_t)bh * SEQ * 64;
  const char* Kg = (const char*)(Kb + (size_t)bh * SEQ * 64);
  const char* Vg = (const char*)(VTb + (size_t)bh * 64 * SEQ);

  // ---- Q fragments (B-operand): col = q = q32, k = d = ds*16 + 8*hi + j
  const int q0w = qb * 128 + w * 32;
  short8 qf[4];
#pragma unroll
  for (int ds = 0; ds < 4; ++ds)
    qf[ds] = *(const short8*)(Qp + (size_t)(q0w + q32) * 64 + ds * 16 + 8 * hi);

  // ---- staging addressing: instr i covers LDS rows i*8..i*8+7;
  // lane l -> row r = i*8 + (l>>3), 16B chunk c' = 16*(l&7);
  // global col byte = c' ^ ((r&7)<<4)   (inverse of read-side swizzle)
  const int srow = l >> 3;                       // == r&7
  const int scol = (16 * (l & 7)) ^ (srow << 4); // 0..127, 16B aligned
  const int i0 = 2 * w, i1 = 2 * w + 1;          // this warp's 2 stage rows-of-8

#define STAGE_KV(buf, kv0)                                                   \
  {                                                                          \
    gload_lds16(Kg + (size_t)((kv0) + i0 * 8 + srow) * 128 + scol,           \
                &lds[buf][0][i0 * 1024]);                                    \
    gload_lds16(Kg + (size_t)((kv0) + i1 * 8 + srow) * 128 + scol,           \
                &lds[buf][0][i1 * 1024]);                                    \
    gload_lds16(Vg + (size_t)(i0 * 8 + srow) * (SEQ * 2) +                   \
                    (size_t)(kv0) * 2 + scol,                                \
                &lds[buf][1][i0 * 1024]);                                    \
    gload_lds16(Vg + (size_t)(i1 * 8 + srow) * (SEQ * 2) +                   \
                    (size_t)(kv0) * 2 + scol,                                \
                &lds[buf][1][i1 * 1024]);                                    \
  }

  STAGE_KV(0, 0);

  f32x16 o0 = {}, o1 = {}; // O^T tiles dt=0,1: col=q32, row d = crow(r,hi)+32dt
  float mrun = -INFINITY, lrun = 0.0f;
  const float cs = 0.125f * 1.44269504088896f; // scale * log2(e)
  const int swz = (q32 & 7) << 4;              // read-side XOR swizzle

#pragma unroll 1
  for (int it = 0; it < 32; ++it) {
    const int kv0 = it * 64;
    const int cur = it & 1;
    __syncthreads(); // drains vmcnt+lgkm: buf[cur] staged, buf[cur^1] free
    if (it < 31) STAGE_KV(cur ^ 1, kv0 + 64);

    // ---- QK^T: 2 kv-tiles x 4 d-slices
    const char* Kt = lds[cur][0];
    f32x16 s0 = {}, s1 = {};
#pragma unroll
    for (int ds = 0; ds < 4; ++ds) {
      const int c = (32 * ds + 16 * hi) ^ swz;
      short8 k0 = *(const short8*)(Kt + q32 * 128 + c);
      short8 k1 = *(const short8*)(Kt + (32 + q32) * 128 + c);
      s0 = __builtin_amdgcn_mfma_f32_32x32x16_bf16(k0, qf[ds], s0, 0, 0, 0);
      s1 = __builtin_amdgcn_mfma_f32_32x32x16_bf16(k1, qf[ds], s1, 0, 0, 0);
    }

    // ---- tile max: max3-friendly triples (T17), then one cross-lane
#define M3F(a, b, c) fmaxf(fmaxf((a), (b)), (c))
    float u0 = M3F(s0[0], s0[1], s0[2]);
    float u1 = M3F(s0[3], s0[4], s0[5]);
    float u2 = M3F(s0[6], s0[7], s0[8]);
    float u3 = M3F(s0[9], s0[10], s0[11]);
    float u4 = M3F(s0[12], s0[13], s0[14]);
    float u5 = M3F(s0[15], s1[0], s1[1]);
    float u6 = M3F(s1[2], s1[3], s1[4]);
    float u7 = M3F(s1[5], s1[6], s1[7]);
    float u8 = M3F(s1[8], s1[9], s1[10]);
    float u9 = M3F(s1[11], s1[12], s1[13]);
    float ua = fmaxf(s1[14], s1[15]);
    float t =
        M3F(M3F(u0, u1, u2), M3F(u3, u4, u5), M3F(M3F(u6, u7, u8), u9, ua));
#undef M3F
    t = fmaxf(t, __shfl_xor(t, 32));
    const float tl = t * cs;

    // ---- defer-max (T13): skip rescale while tile max grows < 8 (log2);
    // P then bounded by 2^8 = 256 — safe in bf16/fp32 accum.
    const bool nores = (__all(tl <= mrun + 8.0f) != 0);
    const float mn = nores ? mrun : fmaxf(mrun, tl);

    float p0[16], p1[16];
    float rs = 0.0f;
#pragma unroll
    for (int i = 0; i < 16; ++i) {
      p0[i] = exp2f(fmaf(s0[i], cs, -mn));
      p1[i] = exp2f(fmaf(s1[i], cs, -mn));
      rs += p0[i] + p1[i];
    }
    rs += __shfl_xor(rs, 32);

    if (!nores) { // rare after warmup (first iter always taken: mrun=-inf)
      const float corr = exp2f(mrun - mn);
      mrun = mn;
      lrun *= corr;
      o0 *= corr;
      o1 *= corr;
    }
    lrun += rs;

    // ---- P -> bf16 words via HW cvt_pk, all in-lane: for slice ks, B-frag
    // word g packs p_t[base+2g], p_t[base+2g+1], t = ks>>1, base = 8*(ks&1)
    uint32_t pw[4][4];
#pragma unroll
    for (int ks = 0; ks < 4; ++ks) {
      const int base = 8 * (ks & 1);
#pragma unroll
      for (int g = 0; g < 4; ++g) {
        float lo = (ks < 2) ? p0[base + 2 * g] : p1[base + 2 * g];
        float hp = (ks < 2) ? p0[base + 2 * g + 1] : p1[base + 2 * g + 1];
        pw[ks][g] = cvt_pk_bf16(lo, hp);
      }
    }

    // ---- PV: A = V^T frag (2 x ds_read_b64, pi-permuted kv), B = P words
    const char* Vt = lds[cur][1];
#pragma unroll
    for (int ks = 0; ks < 4; ++ks) {
      union { short8 v; uint32_t u[4]; } pb;
      pb.u[0] = pw[ks][0];
      pb.u[1] = pw[ks][1];
      pb.u[2] = pw[ks][2];
      pb.u[3] = pw[ks][3];
      const int cA = (32 * ks + 8 * hi) ^ swz;      // kv 16ks+4hi+0..3
      const int cB = (32 * ks + 16 + 8 * hi) ^ swz; // kv 16ks+8+4hi+0..3
      union { short8 v; uint64_t u[2]; } a0, a1;
      a0.u[0] = *(const uint64_t*)(Vt + q32 * 128 + cA);
      a0.u[1] = *(const uint64_t*)(Vt + q32 * 128 + cB);
      a1.u[0] = *(const uint64_t*)(Vt + (32 + q32) * 128 + cA);
      a1.u[1] = *(const uint64_t*)(Vt + (32 + q32) * 128 + cB);
      o0 = __builtin_amdgcn_mfma_f32_32x32x16_bf16(a0.v, pb.v, o0, 0, 0, 0);
      o1 = __builtin_amdgcn_mfma_f32_32x32x16_bf16(a1.v, pb.v, o1, 0, 0, 0);
    }
  }

  // ---- normalize + store: lane q = q0w + q32; d = 32*dt + 8*g + 4*hi + u,
  // regs r = 4g+u of o[dt]; packed via HW cvt_pk
  const float rinv = 1.0f / lrun;
  const size_t orow = (size_t)(b * SEQ + q0w + q32) * 1024 + h * 64;
#pragma unroll
  for (int g = 0; g < 4; ++g) {
    uint2 wa, wb;
    wa.x = cvt_pk_bf16(o0[4 * g + 0] * rinv, o0[4 * g + 1] * rinv);
    wa.y = cvt_pk_bf16(o0[4 * g + 2] * rinv, o0[4 * g + 3] * rinv);
    wb.x = cvt_pk_bf16(o1[4 * g + 0] * rinv, o1[4 * g + 1] * rinv);
    wb.y = cvt_pk_bf16(o1[4 * g + 2] * rinv, o1[4 * g + 3] * rinv);
    *(uint2*)(AO + orow + 8 * g + 4 * hi) = wa;
    *(uint2*)(AO + orow + 32 + 8 * g + 4 * hi) = wb;
  }
#undef STAGE_KV
}

// ---------------------------------------------------------------- launch
extern "C" void kernel_launch(void* const* d_in, const int* in_sizes, int n_in,
                              void* d_out, int out_size, void* d_ws,
                              size_t ws_size, hipStream_t stream) {
  const float* x = (const float*)d_in[0];
  const float* wq = (const float*)d_in[1];
  const float* bq = (const float*)d_in[2];
  const float* wk = (const float*)d_in[3];
  const float* bk = (const float*)d_in[4];
  const float* wv = (const float*)d_in[5];
  const float* bv = (const float*)d_in[6];
  const float* wo = (const float*)d_in[7];
  const float* bo = (const float*)d_in[8];
  float* out = (float*)d_out;
  char* ws = (char*)d_ws;

  // workspace layout (72 MB total)
  __hip_bfloat16* XB = (__hip_bfloat16*)(ws);                  // 16 MB x bf16
  __hip_bfloat16* WT = (__hip_bfloat16*)(ws + (16ull << 20));  // 6 MB WqkvT
  __hip_bfloat16* WOT = (__hip_bfloat16*)(ws + (22ull << 20)); // 2 MB WoT
  __hip_bfloat16* QB = (__hip_bfloat16*)(ws + (24ull << 20));  // 16 MB
  __hip_bfloat16* KB = (__hip_bfloat16*)(ws + (40ull << 20));  // 16 MB
  __hip_bfloat16* VTB = (__hip_bfloat16*)(ws + (56ull << 20)); // 16 MB
  __hip_bfloat16* AO = XB; // reuse: x(bf16) dead after GEMM1

  convert_f32_bf16<<<2048, 256, 0, stream>>>(x, XB, TOK * HIDDEN / 4);
  transpose_to_bf16<<<dim3(16, 16), 256, 0, stream>>>(wq, WT);
  transpose_to_bf16<<<dim3(16, 16), 256, 0, stream>>>(wk, WT + 1024 * 1024);
  transpose_to_bf16<<<dim3(16, 16), 256, 0, stream>>>(wv, WT + 2 * 1024 * 1024);
  transpose_to_bf16<<<dim3(16, 16), 256, 0, stream>>>(wo, WOT);

  // QKV: C[8192,3072] with fused bias + scatter (V transposed)
  gemm128<1, 1024><<<dim3(64, 24), 256, 0, stream>>>(
      XB, WT, nullptr, nullptr, bq, bk, bv, QB, KB, VTB);

  attn32<<<dim3(16, 64), 256, 0, stream>>>(QB, KB, VTB, AO);

  // out = AO @ WoT + bo  (fp32 out)
  gemm128<0, 1024><<<dim3(64, 8), 256, 0, stream>>>(
      AO, WOT, out, bo, nullptr, nullptr, nullptr, nullptr, nullptr, nullptr);
}